// Round 1
// 884.199 us; speedup vs baseline: 1.0079x; 1.0079x over previous
//
#include <hip/hip_runtime.h>

__device__ __forceinline__ float sigf(float v) {
    return 1.0f / (1.0f + __expf(-v));
}
__device__ __forceinline__ float tanh_fast(float v) {
    return 1.0f - 2.0f / (__expf(2.0f * v) + 1.0f);
}

// Wave-per-row streaming, INTERLEAVED row mapping: wave w owns rows
// { w + j*NW : j=0..31 } where NW = gridDim.x = B/32. At any instant all
// resident waves read a dense contiguous slab of H (16 MiB window) instead of
// 2048 lockstep streams at 256-KiB-aligned strides (which alias in the
// channel/L3 interleave and collapsed HBM BW to ~10%).
// Phase A (smallnet/term2): lane k computes row w + k*NW -> o2 kept in regs.
// Phase B (H contraction/term1): whole wave loads one row per step, fully
// coalesced (lane*16B within 1KB-contiguous chunks). Per-lane rm positions are
// row- and l-invariant, so sigmoid(decays) and W_read slices live in VGPRs.
// Cross-lane reduce via 6-level shfl_xor butterfly; lane rr stores its row.
__global__ __launch_bounds__(64)
void organism_main(const float* __restrict__ x,
                   const float* __restrict__ H,
                   const float* __restrict__ W_bit,
                   const float* __restrict__ b_bit,
                   const float* __restrict__ W_bridge,
                   const float* __restrict__ W_read,
                   const float* __restrict__ b_read,
                   const float* __restrict__ W_sh,
                   const float* __restrict__ b_sh,
                   const float* __restrict__ W_eng,
                   const float* __restrict__ b_eng,
                   const float* __restrict__ W_imp,
                   const float* __restrict__ b_imp,
                   const float* __restrict__ W_sur,
                   const float* __restrict__ b_sur,
                   const float* __restrict__ W_gate,
                   const float* __restrict__ b_gate,
                   const float* __restrict__ decays,
                   const float* __restrict__ halt_w,
                   const float* __restrict__ halt_b,
                   float* __restrict__ out)
{
    const int lane = threadIdx.x;            // 0..63
    const int w    = blockIdx.x;             // wave id
    const int NW   = gridDim.x;              // number of waves = B/32
    const size_t arow = (size_t)w + (size_t)(lane & 31) * NW;  // phase-A row

    // ---- issue H prefetch for row j=0 (row w) first (in flight during A) ----
    const float* __restrict__ Hl = H + (size_t)w * 2048 + lane * 4;
    float4 h[8];
#pragma unroll
    for (int it = 0; it < 8; ++it)
        h[it] = *(const float4*)(Hl + it * 256);

    // ================= phase A: small network (term2 + b_read) ============
    float o2[8];
    {
        float xv[8];
        const float4 x0 = *(const float4*)(x + arow * 8);
        const float4 x1 = *(const float4*)(x + arow * 8 + 4);
        xv[0]=x0.x; xv[1]=x0.y; xv[2]=x0.z; xv[3]=x0.w;
        xv[4]=x1.x; xv[5]=x1.y; xv[6]=x1.z; xv[7]=x1.w;

        float s1[32];
#pragma unroll
        for (int i = 0; i < 32; ++i) {
            float a = b_bit[i];
#pragma unroll
            for (int k = 0; k < 8; ++k) a += W_bit[i*8+k] * xv[k];
            s1[i] = a;
        }

        float sa = b_sur[0], ga = b_gate[0];
#pragma unroll
        for (int i = 0; i < 32; ++i) {
            sa += W_sur[i]  * s1[i];
            ga += W_gate[i] * s1[i];
        }
        const float sur = sigf(sa) * sigf(ga);

        float s2[64];
#pragma unroll
        for (int m = 0; m < 64; ++m) {
            float a = 0.0f;
#pragma unroll
            for (int i = 0; i < 32; ++i) a += W_bridge[m*32+i] * s1[i];
            s2[m] = tanh_fast(a);
        }

        float ea = b_eng[0], ia = b_imp[0];
        for (int n = 0; n < 64; ++n) {
            float a = b_sh[n];
#pragma unroll
            for (int m = 0; m < 64; ++m) a += W_sh[n*64+m] * s2[m];
            a = fmaxf(a, 0.0f);
            ea += W_eng[n] * a;
            ia += W_imp[n] * a;
        }
        const float ei = sigf(ea) * sigf(ia);

        float wv[64];
#pragma unroll
        for (int m = 0; m < 64; ++m) wv[m] = sur * s2[m];

#pragma unroll
        for (int o = 0; o < 8; ++o) o2[o] = b_read[o];
        for (int r = 0; r < 8; ++r) {
            float hs = 0.0f;
#pragma unroll
            for (int l = 0; l < 4; ++l) {
                float a = halt_b[l];
#pragma unroll
                for (int m = 0; m < 64; ++m) a += halt_w[(l*8+r)*64+m] * s2[m];
                hs += sigf(a);
            }
            const float gr = 0.25f * ei * hs;
#pragma unroll
            for (int o = 0; o < 8; ++o) {
                float p = 0.0f;
#pragma unroll
                for (int m = 0; m < 64; ++m) p += W_read[o*512 + r*64 + m] * wv[m];
                o2[o] += gr * p;
            }
        }
    }

    // ========== per-lane constants (fixed across rows and l) ==============
    // slot s = hf*4+c  <->  rm = hf*256 + lane*4 + c
    float sd[4][8];
#pragma unroll
    for (int l = 0; l < 4; ++l)
#pragma unroll
        for (int hf = 0; hf < 2; ++hf) {
            const float4 d = *(const float4*)(decays + l*512 + hf*256 + lane*4);
            sd[l][hf*4+0] = 0.25f * sigf(d.x);
            sd[l][hf*4+1] = 0.25f * sigf(d.y);
            sd[l][hf*4+2] = 0.25f * sigf(d.z);
            sd[l][hf*4+3] = 0.25f * sigf(d.w);
        }
    float wrv[8][8];
#pragma unroll
    for (int o = 0; o < 8; ++o)
#pragma unroll
        for (int hf = 0; hf < 2; ++hf) {
            const float4 wq = *(const float4*)(W_read + o*512 + hf*256 + lane*4);
            wrv[o][hf*4+0] = wq.x;
            wrv[o][hf*4+1] = wq.y;
            wrv[o][hf*4+2] = wq.z;
            wrv[o][hf*4+3] = wq.w;
        }

    // ================= phase B: stream 32 interleaved rows =================
#pragma unroll 1
    for (int rr = 0; rr < 32; ++rr) {
        // fold over l: g[slot] = sum_l sd[l][slot] * H[l][rm(slot)]
        float g[8];
#pragma unroll
        for (int hf = 0; hf < 2; ++hf) {
            g[hf*4+0] = sd[0][hf*4+0]*h[hf].x   + sd[1][hf*4+0]*h[2+hf].x
                      + sd[2][hf*4+0]*h[4+hf].x + sd[3][hf*4+0]*h[6+hf].x;
            g[hf*4+1] = sd[0][hf*4+1]*h[hf].y   + sd[1][hf*4+1]*h[2+hf].y
                      + sd[2][hf*4+1]*h[4+hf].y + sd[3][hf*4+1]*h[6+hf].y;
            g[hf*4+2] = sd[0][hf*4+2]*h[hf].z   + sd[1][hf*4+2]*h[2+hf].z
                      + sd[2][hf*4+2]*h[4+hf].z + sd[3][hf*4+2]*h[6+hf].z;
            g[hf*4+3] = sd[0][hf*4+3]*h[hf].w   + sd[1][hf*4+3]*h[2+hf].w
                      + sd[2][hf*4+3]*h[4+hf].w + sd[3][hf*4+3]*h[6+hf].w;
        }

        // prefetch next row's H (h is dead after g); wraps on last iter
        {
            const int nrr = (rr + 1) & 31;
            const float* __restrict__ nb =
                H + ((size_t)w + (size_t)nrr * NW) * 2048 + lane * 4;
#pragma unroll
            for (int it = 0; it < 8; ++it)
                h[it] = *(const float4*)(nb + it * 256);
        }

        // apply W_read slice
        float acc[8];
#pragma unroll
        for (int o = 0; o < 8; ++o) {
            float a = 0.0f;
#pragma unroll
            for (int s = 0; s < 8; ++s) a += wrv[o][s] * g[s];
            acc[o] = a;
        }

        // 6-level butterfly: every lane ends with the full row sums
#pragma unroll
        for (int m = 1; m <= 32; m <<= 1) {
#pragma unroll
            for (int o = 0; o < 8; ++o)
                acc[o] += __shfl_xor(acc[o], m, 64);
        }

        if (lane == rr) {
            float4 a0, a1;
            a0.x = acc[0] + o2[0]; a0.y = acc[1] + o2[1];
            a0.z = acc[2] + o2[2]; a0.w = acc[3] + o2[3];
            a1.x = acc[4] + o2[4]; a1.y = acc[5] + o2[5];
            a1.z = acc[6] + o2[6]; a1.w = acc[7] + o2[7];
            float* op = out + ((size_t)w + (size_t)rr * NW) * 8;
            *(float4*)(op)     = a0;
            *(float4*)(op + 4) = a1;
        }
    }
}

extern "C" void kernel_launch(void* const* d_in, const int* in_sizes, int n_in,
                              void* d_out, int out_size, void* d_ws, size_t ws_size,
                              hipStream_t stream) {
    (void)n_in; (void)d_ws; (void)ws_size; (void)out_size;
    const float* x        = (const float*)d_in[0];
    const float* H        = (const float*)d_in[1];
    const float* W_bit    = (const float*)d_in[2];
    const float* b_bit    = (const float*)d_in[3];
    const float* W_bridge = (const float*)d_in[4];
    const float* W_read   = (const float*)d_in[5];
    const float* b_read   = (const float*)d_in[6];
    const float* W_sh     = (const float*)d_in[7];
    const float* b_sh     = (const float*)d_in[8];
    const float* W_eng    = (const float*)d_in[9];
    const float* b_eng    = (const float*)d_in[10];
    const float* W_imp    = (const float*)d_in[11];
    const float* b_imp    = (const float*)d_in[12];
    const float* W_sur    = (const float*)d_in[13];
    const float* b_sur    = (const float*)d_in[14];
    const float* W_gate   = (const float*)d_in[15];
    const float* b_gate   = (const float*)d_in[16];
    const float* decays   = (const float*)d_in[17];
    const float* halt_w   = (const float*)d_in[18];
    const float* halt_b   = (const float*)d_in[19];
    float* out = (float*)d_out;

    const int B = in_sizes[1] / 2048;            // H is [B, 4*8*16*4]
    hipLaunchKernelGGL(organism_main, dim3(B / 32), dim3(64), 0, stream,
                       x, H, W_bit, b_bit, W_bridge, W_read, b_read,
                       W_sh, b_sh, W_eng, b_eng, W_imp, b_imp,
                       W_sur, b_sur, W_gate, b_gate, decays, halt_w, halt_b,
                       out);
}